// Round 1
// baseline (4794.606 us; speedup 1.0000x reference)
//
#include <hip/hip_runtime.h>

#define NN 20000
#define NE 320000
#define CDIM 16
#define MID 32
#define EPSF 1e-8f

// ---- workspace float offsets ----
#define OFF_STATS1 0           //   8
#define OFF_STATS2 8           // 384  ([k][{sum,sq}][j])
#define OFF_DEG    392         // 20000
#define OFF_AGG0   20392       // 320000
#define OFF_AGG1   340392      // 960000
#define OFF_OUTACC 1300392     // 120000
#define ZERO_FLOATS 1420392
#define OFF_BN1A   1420392     // 192
#define OFF_BN1C   1420584     // 192
#define OFF_BN2A   1420776     // 192
#define OFF_BN2C   1420968     // 192
#define OFF_ECACHE 1421160     // E*4 (float4: r,ux,uy,uz)
#define OFF_H0N    2701160     // 320000
#define OFF_H1N    3021160     // 960000
// total = 3981160 floats ~ 15.9 MB

// spherical-harmonic constants
#define Y0C   0.28209479177387814f
#define Y1C   0.4886025119029199f
#define Y2C1  1.0925484305920792f
#define Y2C2  0.31539156525252005f
#define Y2C3  0.5462742152960396f
#define S2C   0.7071067811865476f
#define S6C   0.4082482904638631f
#define K0C   0.16286750396763996f   // Y0/sqrt(3)

__device__ __forceinline__ void atomAddF(float* p, float v) {
  unsafeAtomicAdd(p, v);   // HW global_atomic_add_f32 on gfx950
}

// Recompute the 2-layer radial MLP output H[32] for network k, one edge.
// All weight accesses are wave-uniform -> scalar loads (SGPR operands).
__device__ __forceinline__ void compute_H(int k, float we, float r,
    const float* __restrict__ rW1, const float* __restrict__ rb1,
    const float* __restrict__ rW2, const float* __restrict__ rb2,
    const float* __restrict__ bn1a, const float* __restrict__ bn1c,
    const float* __restrict__ bn2a, const float* __restrict__ bn2c,
    float* H) {
  const float* W1 = rW1 + k * 64;
  const float* b1 = rb1 + k * 32;
  const float* W2 = rW2 + k * 1024;
  const float* b2 = rb2 + k * 32;
  const float* a1 = bn1a + k * 32;
  const float* c1 = bn1c + k * 32;
  const float* a2 = bn2a + k * 32;
  const float* c2 = bn2c + k * 32;
  float h[MID];
#pragma unroll
  for (int j = 0; j < MID; ++j) {
    float x = fmaf(we, W1[j], fmaf(r, W1[MID + j], b1[j]));
    h[j] = fmaxf(fmaf(x, a1[j], c1[j]), 0.0f);
  }
#pragma unroll
  for (int j = 0; j < MID; ++j) {
    float acc = b2[j];
#pragma unroll
    for (int i = 0; i < MID; ++i) acc = fmaf(h[i], W2[i * MID + j], acc);
    H[j] = fmaxf(fmaf(acc, a2[j], c2[j]), 0.0f);
  }
}

// ---- pass 1: edge geometry cache, degree, layer-1 stat scalars ----
__global__ __launch_bounds__(256) void k_pass1(
    const int* __restrict__ src, const int* __restrict__ dst,
    const float* __restrict__ pos, const float* __restrict__ w,
    float* __restrict__ ws) {
  float lw = 0, lr = 0, lww = 0, lrr = 0, lwr = 0;
  float* deg = ws + OFF_DEG;
  float4* ec = (float4*)(ws + OFF_ECACHE);
  for (int e = blockIdx.x * blockDim.x + threadIdx.x; e < NE;
       e += gridDim.x * blockDim.x) {
    int s = src[e], d = dst[e];
    float dx = pos[3 * d + 0] - pos[3 * s + 0];
    float dy = pos[3 * d + 1] - pos[3 * s + 1];
    float dz = pos[3 * d + 2] - pos[3 * s + 2];
    float r = sqrtf(dx * dx + dy * dy + dz * dz);
    float ri = 1.0f / fmaxf(r, EPSF);
    ec[e] = make_float4(r, dx * ri, dy * ri, dz * ri);
    float we = w[e];
    lw += we; lr += r; lww += we * we; lrr += r * r; lwr += we * r;
    atomAddF(deg + d, 1.0f);
  }
#pragma unroll
  for (int d = 32; d >= 1; d >>= 1) {
    lw += __shfl_xor(lw, d);
    lr += __shfl_xor(lr, d);
    lww += __shfl_xor(lww, d);
    lrr += __shfl_xor(lrr, d);
    lwr += __shfl_xor(lwr, d);
  }
  if ((threadIdx.x & 63) == 0) {
    atomAddF(ws + OFF_STATS1 + 0, lw);
    atomAddF(ws + OFF_STATS1 + 1, lr);
    atomAddF(ws + OFF_STATS1 + 2, lww);
    atomAddF(ws + OFF_STATS1 + 3, lrr);
    atomAddF(ws + OFF_STATS1 + 4, lwr);
  }
}

// ---- finalize BN layer 1 (analytic: x1 linear in (w,r)) ----
__global__ void k_fin1(const float* __restrict__ rW1, const float* __restrict__ rb1,
                       const float* __restrict__ rg1, const float* __restrict__ rbe1,
                       float* __restrict__ ws) {
  int t = threadIdx.x;  // 0..191
  int k = t >> 5, j = t & 31;
  float Sw = ws[OFF_STATS1 + 0], Sr = ws[OFF_STATS1 + 1];
  float Sww = ws[OFF_STATS1 + 2], Srr = ws[OFF_STATS1 + 3], Swr = ws[OFF_STATS1 + 4];
  const float inv = 1.0f / (float)NE;
  float W0 = rW1[k * 64 + j], W1 = rW1[k * 64 + 32 + j], b = rb1[k * 32 + j];
  float mlin = (Sw * W0 + Sr * W1) * inv;
  float mu = mlin + b;
  float ex2 = (Sww * W0 * W0 + Srr * W1 * W1 + 2.0f * Swr * W0 * W1) * inv
            + 2.0f * b * mlin + b * b;
  float var = ex2 - mu * mu;
  float a = rg1[k * 32 + j] * rsqrtf(var + 1e-5f);
  ws[OFF_BN1A + t] = a;
  ws[OFF_BN1C + t] = rbe1[k * 32 + j] - mu * a;
}

// ---- pass 2: layer-2 pre-activation stats (per network via blockIdx.y) ----
__global__ __launch_bounds__(256) void k_stats2(
    const float* __restrict__ w,
    const float* __restrict__ rW1, const float* __restrict__ rb1,
    const float* __restrict__ rW2, const float* __restrict__ rb2,
    float* __restrict__ ws) {
  const int k = blockIdx.y;
  const float* W1 = rW1 + k * 64;
  const float* b1 = rb1 + k * 32;
  const float* W2 = rW2 + k * 1024;
  const float* b2 = rb2 + k * 32;
  const float* a1 = ws + OFF_BN1A + k * 32;
  const float* c1 = ws + OFF_BN1C + k * 32;
  const float4* ec = (const float4*)(ws + OFF_ECACHE);
  float lsum[MID], lsq[MID];
#pragma unroll
  for (int j = 0; j < MID; ++j) { lsum[j] = 0.0f; lsq[j] = 0.0f; }
  for (int e = blockIdx.x * blockDim.x + threadIdx.x; e < NE;
       e += gridDim.x * blockDim.x) {
    float r = ec[e].x;
    float we = w[e];
    float h[MID];
#pragma unroll
    for (int j = 0; j < MID; ++j) {
      float x = fmaf(we, W1[j], fmaf(r, W1[MID + j], b1[j]));
      h[j] = fmaxf(fmaf(x, a1[j], c1[j]), 0.0f);
    }
#pragma unroll
    for (int j = 0; j < MID; ++j) {
      float acc = b2[j];
#pragma unroll
      for (int i = 0; i < MID; ++i) acc = fmaf(h[i], W2[i * MID + j], acc);
      lsum[j] += acc;
      lsq[j] = fmaf(acc, acc, lsq[j]);
    }
  }
#pragma unroll
  for (int j = 0; j < MID; ++j) {
    float v1 = lsum[j], v2 = lsq[j];
#pragma unroll
    for (int d = 32; d >= 1; d >>= 1) {
      v1 += __shfl_xor(v1, d);
      v2 += __shfl_xor(v2, d);
    }
    if ((threadIdx.x & 63) == 0) {
      atomAddF(ws + OFF_STATS2 + k * 64 + j, v1);
      atomAddF(ws + OFF_STATS2 + k * 64 + 32 + j, v2);
    }
  }
}

// ---- finalize BN layer 2 ----
__global__ void k_fin2(const float* __restrict__ rg2, const float* __restrict__ rbe2,
                       float* __restrict__ ws) {
  int t = threadIdx.x;  // 0..191
  int k = t >> 5, j = t & 31;
  const float inv = 1.0f / (float)NE;
  float mu = ws[OFF_STATS2 + k * 64 + j] * inv;
  float ex2 = ws[OFF_STATS2 + k * 64 + 32 + j] * inv;
  float var = ex2 - mu * mu;
  float a = rg2[t] * rsqrtf(var + 1e-5f);
  ws[OFF_BN2A + t] = a;
  ws[OFF_BN2C + t] = rbe2[t] - mu * a;
}

// ---- stage A: per-edge messages m0 (C), m1 (C,3) -> atomic scatter ----
__global__ __launch_bounds__(256) void k_passA(
    const int* __restrict__ src, const int* __restrict__ dst,
    const float* __restrict__ cI, const float* __restrict__ vI,
    const float* __restrict__ w,
    const float* __restrict__ rW1, const float* __restrict__ rb1,
    const float* __restrict__ rW2, const float* __restrict__ rb2,
    const float* __restrict__ w00, const float* __restrict__ b00,
    const float* __restrict__ w01, const float* __restrict__ b01,
    const float* __restrict__ w10, const float* __restrict__ b10,
    const float* __restrict__ w11, const float* __restrict__ b11,
    float* __restrict__ ws) {
  const float4* ec = (const float4*)(ws + OFF_ECACHE);
  const float* bn1a = ws + OFF_BN1A;
  const float* bn1c = ws + OFF_BN1C;
  const float* bn2a = ws + OFF_BN2A;
  const float* bn2c = ws + OFF_BN2C;
  float* agg0 = ws + OFF_AGG0;
  float* agg1 = ws + OFF_AGG1;
  for (int e = blockIdx.x * blockDim.x + threadIdx.x; e < NE;
       e += gridDim.x * blockDim.x) {
    int s = src[e], d = dst[e];
    float4 E4 = ec[e];
    float r = E4.x, ux = E4.y, uy = E4.z, uz = E4.w;
    float we = w[e];
    float cs = cI[s];
    float v0 = vI[3 * s + 0], v1 = vI[3 * s + 1], v2 = vI[3 * s + 2];
    // Y1 = c*[y,z,x]
    float y10 = Y1C * uy, y11 = Y1C * uz, y12 = Y1C * ux;
    float y20 = Y2C1 * ux * uy, y21 = Y2C1 * uy * uz;
    float y22 = Y2C2 * (3.0f * uz * uz - 1.0f);
    float y23 = Y2C1 * ux * uz, y24 = Y2C3 * (ux * ux - uy * uy);
    // K2 (symmetric)
    float S00 = -S6C * y22 - S2C * y24;
    float S11 = 2.0f * S6C * y22;
    float S22 = -S6C * y22 + S2C * y24;
    float S01 = S2C * y21, S02 = S2C * y20, S12 = S2C * y23;
    // KV[f][a] = sum_b K_f[a][b] * v_src[b]
    float KV[3][3];
    KV[0][0] = K0C * v0; KV[0][1] = K0C * v1; KV[0][2] = K0C * v2;
    KV[1][0] = S2C * (y12 * v1 - y11 * v2);
    KV[1][1] = S2C * (y10 * v2 - y12 * v0);
    KV[1][2] = S2C * (y11 * v0 - y10 * v1);
    KV[2][0] = S00 * v0 + S01 * v1 + S02 * v2;
    KV[2][1] = S01 * v0 + S11 * v1 + S12 * v2;
    KV[2][2] = S02 * v0 + S12 * v1 + S22 * v2;
    float dY1v = y10 * v0 + y11 * v1 + y12 * v2;

    float H[MID];
    float m0[CDIM], m1[CDIM * 3];

    // net 0 (k00 path): m0 = R00 * Y0 * c_src
    compute_H(0, we, r, rW1, rb1, rW2, rb2, bn1a, bn1c, bn2a, bn2c, H);
    float f0 = Y0C * cs;
#pragma unroll
    for (int co = 0; co < CDIM; ++co) {
      float acc = b00[co];
#pragma unroll
      for (int i = 0; i < MID; ++i) acc = fmaf(H[i], w00[i * CDIM + co], acc);
      m0[co] = acc * f0;
    }
    // net 2 (k10 path): m0 += R10 * (Y1 . v_src)
    compute_H(2, we, r, rW1, rb1, rW2, rb2, bn1a, bn1c, bn2a, bn2c, H);
#pragma unroll
    for (int co = 0; co < CDIM; ++co) {
      float acc = b10[co];
#pragma unroll
      for (int i = 0; i < MID; ++i) acc = fmaf(H[i], w10[i * CDIM + co], acc);
      m0[co] = fmaf(acc, dY1v, m0[co]);
    }
    // net 1 (k01 path): m1 = R01 * c_src * Y1[a]
    compute_H(1, we, r, rW1, rb1, rW2, rb2, bn1a, bn1c, bn2a, bn2c, H);
    float cy0 = cs * y10, cy1 = cs * y11, cy2 = cs * y12;
#pragma unroll
    for (int co = 0; co < CDIM; ++co) {
      float acc = b01[co];
#pragma unroll
      for (int i = 0; i < MID; ++i) acc = fmaf(H[i], w01[i * CDIM + co], acc);
      m1[co * 3 + 0] = acc * cy0;
      m1[co * 3 + 1] = acc * cy1;
      m1[co * 3 + 2] = acc * cy2;
    }
    // net 3 (k11 path): m1[co][a] += sum_f R11[co,f] * KV[f][a]
    compute_H(3, we, r, rW1, rb1, rW2, rb2, bn1a, bn1c, bn2a, bn2c, H);
#pragma unroll
    for (int co = 0; co < CDIM; ++co) {
#pragma unroll
      for (int f = 0; f < 3; ++f) {
        float acc = b11[co * 3 + f];
#pragma unroll
        for (int i = 0; i < MID; ++i) acc = fmaf(H[i], w11[i * 48 + co * 3 + f], acc);
        m1[co * 3 + 0] = fmaf(acc, KV[f][0], m1[co * 3 + 0]);
        m1[co * 3 + 1] = fmaf(acc, KV[f][1], m1[co * 3 + 1]);
        m1[co * 3 + 2] = fmaf(acc, KV[f][2], m1[co * 3 + 2]);
      }
    }
    float* p0 = agg0 + d * CDIM;
    float* p1 = agg1 + d * CDIM * 3;
#pragma unroll
    for (int co = 0; co < CDIM; ++co) atomAddF(p0 + co, m0[co]);
#pragma unroll
    for (int q = 0; q < CDIM * 3; ++q) atomAddF(p1 + q, m1[q]);
  }
}

// ---- node update A: normalize aggregates, norm_bias -> h0n, h1n ----
__global__ __launch_bounds__(256) void k_nodeA(
    const float* __restrict__ cI, const float* __restrict__ vI,
    const float* __restrict__ selfA0, const float* __restrict__ selfA1,
    const float* __restrict__ nbias0, const float* __restrict__ nbias1,
    float* __restrict__ ws) {
  int idx = blockIdx.x * blockDim.x + threadIdx.x;
  if (idx >= NN * CDIM) return;
  int n = idx >> 4, co = idx & 15;
  float dg = ws[OFF_DEG + n];
  float iv = 1.0f / fmaxf(dg, 1.0f);
  float mk = dg > 0.0f ? 1.0f : 0.0f;
  float x0 = ws[OFF_AGG0 + idx] * iv + selfA0[co] * cI[n] * mk;
  float n0 = sqrtf(x0 * x0 + 1e-12f);
  ws[OFF_H0N + idx] = fmaxf(n0 + nbias0[co], 0.0f) * (x0 / fmaxf(n0, EPSF));
  float xa = ws[OFF_AGG1 + idx * 3 + 0] * iv + selfA1[co] * vI[3 * n + 0] * mk;
  float xb = ws[OFF_AGG1 + idx * 3 + 1] * iv + selfA1[co] * vI[3 * n + 1] * mk;
  float xc = ws[OFF_AGG1 + idx * 3 + 2] * iv + selfA1[co] * vI[3 * n + 2] * mk;
  float nv = sqrtf(xa * xa + xb * xb + xc * xc + 1e-12f);
  float sc = fmaxf(nv + nbias1[co], 0.0f) / fmaxf(nv, EPSF);
  ws[OFF_H1N + idx * 3 + 0] = xa * sc;
  ws[OFF_H1N + idx * 3 + 1] = xb * sc;
  ws[OFF_H1N + idx * 3 + 2] = xc * sc;
}

// ---- stage B: per-edge output messages -> atomic scatter ----
__global__ __launch_bounds__(256) void k_passB(
    const int* __restrict__ src, const int* __restrict__ dst,
    const float* __restrict__ w,
    const float* __restrict__ rW1, const float* __restrict__ rb1,
    const float* __restrict__ rW2, const float* __restrict__ rb2,
    const float* __restrict__ wb01, const float* __restrict__ bb01,
    const float* __restrict__ wb11, const float* __restrict__ bb11,
    float* __restrict__ ws) {
  const float4* ec = (const float4*)(ws + OFF_ECACHE);
  const float* bn1a = ws + OFF_BN1A;
  const float* bn1c = ws + OFF_BN1C;
  const float* bn2a = ws + OFF_BN2A;
  const float* bn2c = ws + OFF_BN2C;
  float* outacc = ws + OFF_OUTACC;
  for (int e = blockIdx.x * blockDim.x + threadIdx.x; e < NE;
       e += gridDim.x * blockDim.x) {
    int s = src[e], d = dst[e];
    float4 E4 = ec[e];
    float r = E4.x, ux = E4.y, uy = E4.z, uz = E4.w;
    float we = w[e];
    float y10 = Y1C * uy, y11 = Y1C * uz, y12 = Y1C * ux;
    float y20 = Y2C1 * ux * uy, y21 = Y2C1 * uy * uz;
    float y22 = Y2C2 * (3.0f * uz * uz - 1.0f);
    float y23 = Y2C1 * ux * uz, y24 = Y2C3 * (ux * ux - uy * uy);
    float S00 = -S6C * y22 - S2C * y24;
    float S11 = 2.0f * S6C * y22;
    float S22 = -S6C * y22 + S2C * y24;
    float S01 = S2C * y21, S02 = S2C * y20, S12 = S2C * y23;

    float H[MID];
    // net 4: A[o] = sum_ci Rb01[o,ci] * h0n[src,ci]
    compute_H(4, we, r, rW1, rb1, rW2, rb2, bn1a, bn1c, bn2a, bn2c, H);
    const float* h0p = ws + OFF_H0N + s * CDIM;
    float A0 = 0.0f, A1 = 0.0f;
#pragma unroll
    for (int ci = 0; ci < CDIM; ++ci) {
      float t0 = h0p[ci];
      float R0 = bb01[ci];
      float R1 = bb01[CDIM + ci];
#pragma unroll
      for (int i = 0; i < MID; ++i) {
        float hi = H[i];
        R0 = fmaf(hi, wb01[i * 32 + ci], R0);
        R1 = fmaf(hi, wb01[i * 32 + CDIM + ci], R1);
      }
      A0 = fmaf(R0, t0, A0);
      A1 = fmaf(R1, t0, A1);
    }
    // net 5: G[o][f][b] = sum_ci Rb11[o,ci,f] * h1n[src,ci,b]
    compute_H(5, we, r, rW1, rb1, rW2, rb2, bn1a, bn1c, bn2a, bn2c, H);
    const float* h1p = ws + OFF_H1N + s * CDIM * 3;
    float G[2][3][3];
#pragma unroll
    for (int o = 0; o < 2; ++o)
#pragma unroll
      for (int f = 0; f < 3; ++f) {
        G[o][f][0] = 0.0f; G[o][f][1] = 0.0f; G[o][f][2] = 0.0f;
      }
#pragma unroll
    for (int ci = 0; ci < CDIM; ++ci) {
      float t1b0 = h1p[ci * 3 + 0], t1b1 = h1p[ci * 3 + 1], t1b2 = h1p[ci * 3 + 2];
#pragma unroll
      for (int o = 0; o < 2; ++o) {
#pragma unroll
        for (int f = 0; f < 3; ++f) {
          float R = bb11[o * 48 + ci * 3 + f];
#pragma unroll
          for (int i = 0; i < MID; ++i)
            R = fmaf(H[i], wb11[i * 96 + o * 48 + ci * 3 + f], R);
          G[o][f][0] = fmaf(R, t1b0, G[o][f][0]);
          G[o][f][1] = fmaf(R, t1b1, G[o][f][1]);
          G[o][f][2] = fmaf(R, t1b2, G[o][f][2]);
        }
      }
    }
    // mB[o][a] = A_o*Y1[a] + k0*G[o][0][a] + K1-contr + K2-contr
    float* op = outacc + d * 6;
#pragma unroll
    for (int o = 0; o < 2; ++o) {
      float Ao = (o == 0) ? A0 : A1;
      float mB0 = Ao * y10 + K0C * G[o][0][0]
                + S2C * (y12 * G[o][1][1] - y11 * G[o][1][2])
                + S00 * G[o][2][0] + S01 * G[o][2][1] + S02 * G[o][2][2];
      float mB1 = Ao * y11 + K0C * G[o][0][1]
                + S2C * (y10 * G[o][1][2] - y12 * G[o][1][0])
                + S01 * G[o][2][0] + S11 * G[o][2][1] + S12 * G[o][2][2];
      float mB2 = Ao * y12 + K0C * G[o][0][2]
                + S2C * (y11 * G[o][1][0] - y10 * G[o][1][1])
                + S02 * G[o][2][0] + S12 * G[o][2][1] + S22 * G[o][2][2];
      atomAddF(op + o * 3 + 0, mB0);
      atomAddF(op + o * 3 + 1, mB1);
      atomAddF(op + o * 3 + 2, mB2);
    }
  }
}

// ---- node update B: final output ----
__global__ __launch_bounds__(256) void k_nodeB(
    const float* __restrict__ selfB1, float* __restrict__ out,
    const float* __restrict__ ws) {
  int idx = blockIdx.x * blockDim.x + threadIdx.x;
  if (idx >= NN * 6) return;
  int n = idx / 6;
  int rem = idx - n * 6;
  int o = rem / 3, a = rem - o * 3;
  float dg = ws[OFF_DEG + n];
  float iv = 1.0f / fmaxf(dg, 1.0f);
  float mk = dg > 0.0f ? 1.0f : 0.0f;
  const float* h1p = ws + OFF_H1N + n * CDIM * 3;
  float self = 0.0f;
#pragma unroll
  for (int ci = 0; ci < CDIM; ++ci)
    self = fmaf(selfB1[o * CDIM + ci], h1p[ci * 3 + a], self);
  out[idx] = ws[OFF_OUTACC + idx] * iv + self * mk;
}

extern "C" void kernel_launch(void* const* d_in, const int* in_sizes, int n_in,
                              void* d_out, int out_size, void* d_ws, size_t ws_size,
                              hipStream_t stream) {
  (void)in_sizes; (void)n_in; (void)out_size; (void)ws_size;
  const int* src = (const int*)d_in[0];
  const int* dst = (const int*)d_in[1];
  const float* pos = (const float*)d_in[2];
  const float* cI = (const float*)d_in[3];
  const float* vI = (const float*)d_in[4];
  const float* w = (const float*)d_in[5];
  const float* rW1 = (const float*)d_in[6];
  const float* rb1 = (const float*)d_in[7];
  const float* rg1 = (const float*)d_in[8];
  const float* rbe1 = (const float*)d_in[9];
  const float* rW2 = (const float*)d_in[10];
  const float* rb2 = (const float*)d_in[11];
  const float* rg2 = (const float*)d_in[12];
  const float* rbe2 = (const float*)d_in[13];
  const float* w3_a00 = (const float*)d_in[14];
  const float* b3_a00 = (const float*)d_in[15];
  const float* w3_a01 = (const float*)d_in[16];
  const float* b3_a01 = (const float*)d_in[17];
  const float* w3_a10 = (const float*)d_in[18];
  const float* b3_a10 = (const float*)d_in[19];
  const float* w3_a11 = (const float*)d_in[20];
  const float* b3_a11 = (const float*)d_in[21];
  const float* w3_b01 = (const float*)d_in[22];
  const float* b3_b01 = (const float*)d_in[23];
  const float* w3_b11 = (const float*)d_in[24];
  const float* b3_b11 = (const float*)d_in[25];
  const float* selfA0 = (const float*)d_in[26];
  const float* selfA1 = (const float*)d_in[27];
  const float* selfB1 = (const float*)d_in[28];
  const float* nbias0 = (const float*)d_in[29];
  const float* nbias1 = (const float*)d_in[30];
  float* ws = (float*)d_ws;
  float* out = (float*)d_out;

  hipMemsetAsync(d_ws, 0, (size_t)ZERO_FLOATS * sizeof(float), stream);

  k_pass1<<<1250, 256, 0, stream>>>(src, dst, pos, w, ws);
  k_fin1<<<1, 192, 0, stream>>>(rW1, rb1, rg1, rbe1, ws);
  k_stats2<<<dim3(128, 6), 256, 0, stream>>>(w, rW1, rb1, rW2, rb2, ws);
  k_fin2<<<1, 192, 0, stream>>>(rg2, rbe2, ws);
  k_passA<<<1250, 256, 0, stream>>>(src, dst, cI, vI, w, rW1, rb1, rW2, rb2,
                                    w3_a00, b3_a00, w3_a01, b3_a01,
                                    w3_a10, b3_a10, w3_a11, b3_a11, ws);
  k_nodeA<<<1250, 256, 0, stream>>>(cI, vI, selfA0, selfA1, nbias0, nbias1, ws);
  k_passB<<<1250, 256, 0, stream>>>(src, dst, w, rW1, rb1, rW2, rb2,
                                    w3_b01, b3_b01, w3_b11, b3_b11, ws);
  k_nodeB<<<469, 256, 0, stream>>>(selfB1, out, ws);
}